// Round 2
// baseline (1049.688 us; speedup 1.0000x reference)
//
#include <hip/hip_runtime.h>

// CRF log-likelihood: B=256, S=2048, L=64, START=62, END=63.
// One block (4 waves, 256 threads) per batch element; lane i owns state i.
// j-split matvec: wave w owns j in [16w,16w+16) -> P slice = 16 VGPRs (no spill).
// Partials exchanged via 2KB double-buffered LDS with an LDS-only barrier
// (s_waitcnt lgkmcnt(0); s_barrier) so the global logits prefetch stays in flight.
// Lagged renorm: rho_s = readlane(r_s, 0) applied at step s+1 (off critical path).

#define Bsz 256
#define Ssz 2048
#define START_ 62
#define END_ 63

__device__ __forceinline__ float rdlane(float v, int l) {
    return __int_as_float(__builtin_amdgcn_readlane(__float_as_int(v), l));
}

// Barrier that drains ONLY LDS ops (keeps global-load prefetch in flight,
// unlike __syncthreads() which drains vmcnt too).
__device__ __forceinline__ void barrier_lds_only() {
    asm volatile("s_waitcnt lgkmcnt(0)\n\ts_barrier" ::: "memory");
}

__device__ __forceinline__ float wave_sum(float v) {
#pragma unroll
    for (int m = 32; m >= 1; m >>= 1) v += __shfl_xor(v, m, 64);
    return v;
}

__global__ __launch_bounds__(256, 1)
void crf_kernel(const float* __restrict__ logits,
                const float* __restrict__ transition,
                const int* __restrict__ labels,
                const int* __restrict__ lens,
                float* __restrict__ out)
{
    const int b    = blockIdx.x;
    const int tid  = threadIdx.x;
    const int lane = tid & 63;
    const int w    = tid >> 6;                 // wave id 0..3
    const float L2E = 1.4426950408889634f;
    const float LN2 = 0.6931471805599453f;

    __shared__ float part[2][256];             // [parity][w*64 + lane]

    const int len = lens[b];                   // 1..2048, uniform per block
    const float* lrow = logits + (size_t)b * (Ssz * 64);

    // P slice: lane i holds exp(T[i][16w+j]), j=0..15  (16 VGPRs)
    float P[16];
#pragma unroll
    for (int j = 0; j < 16; ++j)
        P[j] = __builtin_amdgcn_exp2f(transition[lane * 64 + 16 * w + j] * L2E);

    // r: base-2 alpha, renorm lagged by one step; true alpha2 = r + C.
    float r   = (lane == START_) ? 0.0f : -100.0f * L2E;
    float C   = 0.0f;
    float rho = 0.0f;                          // shift to apply THIS step

    // 4-deep rolling logits prefetch (coalesced 256B/row; 4x redundant across
    // waves but L1-served).
    float lgbuf[4];
#pragma unroll
    for (int d = 0; d < 4; ++d) {
        int s0 = (d < len) ? d : (len - 1);
        lgbuf[d] = lrow[s0 * 64 + lane];
    }

    for (int s = 0; s < len; ++s) {
        const float lg = lgbuf[s & 3];
        int pf = s + 4; pf = (pf < len) ? pf : (len - 1);
        lgbuf[s & 3] = lrow[pf * 64 + lane];   // prefetch 4 ahead

        const float E = __builtin_amdgcn_exp2f(r);   // one exp per step

        // Batch the 16 lane-broadcasts into SGPRs first (hides the
        // VALU-writes-SGPR -> VALU-reads-SGPR hazard), then 16 FMAs.
        float e[16];
#pragma unroll
        for (int j = 0; j < 16; ++j) e[j] = rdlane(E, 16 * w + j);

        float a0 = 0.f, a1 = 0.f, a2 = 0.f, a3 = 0.f;
#pragma unroll
        for (int j = 0; j < 16; j += 4) {
            a0 = __builtin_fmaf(P[j + 0], e[j + 0], a0);
            a1 = __builtin_fmaf(P[j + 1], e[j + 1], a1);
            a2 = __builtin_fmaf(P[j + 2], e[j + 2], a2);
            a3 = __builtin_fmaf(P[j + 3], e[j + 3], a3);
        }
        const float partial = (a0 + a1) + (a2 + a3);
        const float hold = __builtin_fmaf(lg, L2E, -rho);  // off critical path

        float* pp = &part[s & 1][0];
        pp[tid] = partial;                     // conflict-free (tid-contiguous)
        barrier_lds_only();
        // 4 partials, stride 64 floats: 2-way bank aliasing only (free)
        const float ssum = (pp[lane] + pp[lane + 64])
                         + (pp[lane + 128] + pp[lane + 192]);

        const float rnew = __builtin_amdgcn_logf(ssum) + hold;
        C  += rho;                             // accumulate the shift just applied
        rho = rdlane(rnew, 0);                 // next step's shift (lagged)
        r   = rnew;
    }

    barrier_lds_only();                        // protect part[] reuse below

    // Gold path score, split across all 256 threads.
    const int* lab = labels + (size_t)b * Ssz;
    float g = 0.0f;
    for (int s = tid; s < len; s += 256) {
        const int l1 = lab[s];
        const int l0 = (s == 0) ? START_ : lab[s - 1];
        g += lrow[s * 64 + l1] + transition[l1 * 64 + l0];
        if (s == len - 1) g += transition[END_ * 64 + l1];  // END transition
    }
    g = wave_sum(g);
    if (lane == 0) part[0][w] = g;
    barrier_lds_only();

    if (w == 0) {
        const float Pend = __builtin_amdgcn_exp2f(transition[END_ * 64 + lane] * L2E);
        const float tot  = wave_sum(__builtin_amdgcn_exp2f(r) * Pend);
        const float norm = LN2 * (C + __builtin_amdgcn_logf(tot));
        const float gold = (part[0][0] + part[0][1]) + (part[0][2] + part[0][3]);
        if (lane == 0) out[b] = gold - norm;
    }
}

extern "C" void kernel_launch(void* const* d_in, const int* in_sizes, int n_in,
                              void* d_out, int out_size, void* d_ws, size_t ws_size,
                              hipStream_t stream) {
    const float* logits     = (const float*)d_in[0];
    const float* transition = (const float*)d_in[1];
    const int*   labels     = (const int*)d_in[2];
    const int*   lens       = (const int*)d_in[3];
    float*       out        = (float*)d_out;

    crf_kernel<<<dim3(Bsz), dim3(256), 0, stream>>>(
        logits, transition, labels, lens, out);
}